// Round 1
// baseline (42499.197 us; speedup 1.0000x reference)
//
#include <hip/hip_runtime.h>
#include <hip/hip_bf16.h>
#include <math.h>

// ---------------------------------------------------------------------------
// VQGAN forward, fp32 baseline.
// Layout notes:
//  - All tensors NCHW, fp32.
//  - VQ operates on rows of row-major-flattened z: each row = z[b,ch,h,0:32]
//    (the reference preserves the original torch reshape bug).
//  - d_out = [recon 16*3*256*256 | q 16*32*32*32 | idx-as-float 16384]
// ---------------------------------------------------------------------------

#define EPS 1e-5f

// ============================ conv k4 s2 p1 ================================
// Each thread computes 4 consecutive ow outputs for one (n,co,oh).
// n,co derived from blockIdx only -> weight loads are scalar (SMEM).
__global__ __launch_bounds__(256) void conv4s2(
    const float* __restrict__ x, const float* __restrict__ w,
    const float* __restrict__ bias, float* __restrict__ y,
    int N, int Cin, int Cout, int Hin, int Win, int Hout, int Wout)
{
    const int Wt = Wout >> 2;                 // tiles along width
    const int bpp = (Hout * Wt) >> 8;         // blocks per (n,co) plane
    const int plane = blockIdx.x / bpp;       // scalar
    const int pb = blockIdx.x - plane * bpp;  // scalar
    const int co = plane % Cout;              // scalar
    const int n  = plane / Cout;              // scalar
    const int local = pb * 256 + threadIdx.x;
    const int wt = local % Wt;
    const int oh = local / Wt;
    const int iw0 = (wt << 3) - 1;            // leftmost input col touched
    const int ih0 = (oh << 1) - 1;            // top input row touched

    const float* __restrict__ wp0 = w + (size_t)co * Cin * 16;
    const float* __restrict__ xn  = x + (size_t)n * Cin * Hin * Win;

    float acc0 = 0.f, acc1 = 0.f, acc2 = 0.f, acc3 = 0.f;

    const bool interior = (ih0 >= 0) && (ih0 + 3 < Hin) && (iw0 >= 0) && (iw0 + 9 < Win);

    if (interior) {
        for (int ci = 0; ci < Cin; ++ci) {
            const float* xp = xn + (size_t)ci * Hin * Win + (size_t)ih0 * Win + iw0;
            const float* wp = wp0 + ci * 16;
            float xv[4][10];
            #pragma unroll
            for (int k = 0; k < 4; ++k) {
                #pragma unroll
                for (int j = 0; j < 10; ++j) xv[k][j] = xp[k * Win + j];
            }
            #pragma unroll
            for (int kh = 0; kh < 4; ++kh) {
                #pragma unroll
                for (int kw = 0; kw < 4; ++kw) {
                    float wv = wp[kh * 4 + kw];
                    acc0 = fmaf(xv[kh][kw + 0], wv, acc0);
                    acc1 = fmaf(xv[kh][kw + 2], wv, acc1);
                    acc2 = fmaf(xv[kh][kw + 4], wv, acc2);
                    acc3 = fmaf(xv[kh][kw + 6], wv, acc3);
                }
            }
        }
    } else {
        bool rv[4]; int ro[4];
        #pragma unroll
        for (int k = 0; k < 4; ++k) {
            int r = ih0 + k;
            rv[k] = (r >= 0) && (r < Hin);
            ro[k] = rv[k] ? r : 0;
        }
        bool cv[10]; int cc[10];
        #pragma unroll
        for (int j = 0; j < 10; ++j) {
            int c = iw0 + j;
            cv[j] = (c >= 0) && (c < Win);
            cc[j] = cv[j] ? c : 0;
        }
        for (int ci = 0; ci < Cin; ++ci) {
            const float* xp = xn + (size_t)ci * Hin * Win;
            const float* wp = wp0 + ci * 16;
            float xv[4][10];
            #pragma unroll
            for (int k = 0; k < 4; ++k) {
                #pragma unroll
                for (int j = 0; j < 10; ++j) {
                    float v = xp[(size_t)ro[k] * Win + cc[j]];
                    xv[k][j] = (rv[k] && cv[j]) ? v : 0.f;
                }
            }
            #pragma unroll
            for (int kh = 0; kh < 4; ++kh) {
                #pragma unroll
                for (int kw = 0; kw < 4; ++kw) {
                    float wv = wp[kh * 4 + kw];
                    acc0 = fmaf(xv[kh][kw + 0], wv, acc0);
                    acc1 = fmaf(xv[kh][kw + 2], wv, acc1);
                    acc2 = fmaf(xv[kh][kw + 4], wv, acc2);
                    acc3 = fmaf(xv[kh][kw + 6], wv, acc3);
                }
            }
        }
    }

    float b = bias[co];
    float4 out;
    out.x = acc0 + b; out.y = acc1 + b; out.z = acc2 + b; out.w = acc3 + b;
    float* yp = y + ((size_t)plane * Hout + oh) * Wout + (wt << 2);
    *(float4*)yp = out;
}

// ======================= GroupNorm(32) + SiLU, in place ====================
// One block per (batch, group). Two passes: stats, then normalize+SiLU.
__global__ __launch_bounds__(256) void gn_silu(
    float* __restrict__ y, const float* __restrict__ gamma,
    const float* __restrict__ beta, int C, int HWshift, int grpC)
{
    const int b = blockIdx.x >> 5;
    const int g = blockIdx.x & 31;
    const size_t base = ((size_t)b * C + (size_t)g * grpC) << HWshift;
    const int count = grpC << HWshift;

    float s = 0.f, ss = 0.f;
    for (int i = threadIdx.x; i < count; i += 256) {
        float v = y[base + i];
        s += v;
        ss = fmaf(v, v, ss);
    }
    __shared__ float sh0[256];
    __shared__ float sh1[256];
    sh0[threadIdx.x] = s; sh1[threadIdx.x] = ss;
    __syncthreads();
    for (int off = 128; off > 0; off >>= 1) {
        if (threadIdx.x < off) {
            sh0[threadIdx.x] += sh0[threadIdx.x + off];
            sh1[threadIdx.x] += sh1[threadIdx.x + off];
        }
        __syncthreads();
    }
    const float inv = 1.f / (float)count;
    const float mean = sh0[0] * inv;
    const float var  = sh1[0] * inv - mean * mean;
    const float rstd = rsqrtf(var + EPS);

    for (int i = threadIdx.x; i < count; i += 256) {
        int c = g * grpC + (i >> HWshift);
        float v = y[base + i];
        float t = (v - mean) * rstd * gamma[c] + beta[c];
        y[base + i] = t / (1.f + __expf(-t));   // SiLU
    }
}

// ============================== 1x1 conv ===================================
__global__ __launch_bounds__(256) void conv1x1(
    const float* __restrict__ x, const float* __restrict__ w,
    const float* __restrict__ bias, float* __restrict__ y,
    int N, int Cin, int Cout, int HW)
{
    const int bpp = HW >> 8;
    const int plane = blockIdx.x / bpp;
    const int pb = blockIdx.x - plane * bpp;
    const int co = plane % Cout;
    const int n  = plane / Cout;
    const int s = pb * 256 + threadIdx.x;
    const float* xp = x + (size_t)n * Cin * HW + s;
    const float* wp = w + (size_t)co * Cin;
    float acc = bias[co];
    for (int ci = 0; ci < Cin; ++ci)
        acc = fmaf(xp[(size_t)ci * HW], wp[ci], acc);
    y[(size_t)plane * HW + s] = acc;
}

// ============================== VQ lookup ==================================
__global__ __launch_bounds__(256) void cb_norm(
    const float* __restrict__ cb, float* __restrict__ cn)
{
    int j = blockIdx.x * 256 + threadIdx.x;   // 1024 total
    const float* c = cb + (size_t)j * 32;
    float s = 0.f;
    #pragma unroll
    for (int k = 0; k < 32; ++k) s = fmaf(c[k], c[k], s);
    cn[j] = s;
}

// One wave per row (row = 32 contiguous floats of z). d = |z|^2+|c|^2-2 z.c
__global__ __launch_bounds__(256) void vq_kernel(
    const float* __restrict__ z, const float* __restrict__ cb,
    const float* __restrict__ cn, float* __restrict__ q,
    float* __restrict__ idxf)
{
    const int row = blockIdx.x * 4 + (threadIdx.x >> 6);
    const int lane = threadIdx.x & 63;
    const float* zr = z + (size_t)row * 32;
    float zreg[32];
    #pragma unroll
    for (int k = 0; k < 32; ++k) zreg[k] = zr[k];
    float zn = 0.f;
    #pragma unroll
    for (int k = 0; k < 32; ++k) zn = fmaf(zreg[k], zreg[k], zn);

    float best = 3.4e38f;
    int bj = 0;
    for (int ii = 0; ii < 16; ++ii) {
        int j = lane * 16 + ii;               // lane-ascending code order
        const float* c = cb + (size_t)j * 32;
        float dot = 0.f;
        #pragma unroll
        for (int k = 0; k < 32; ++k) dot = fmaf(zreg[k], c[k], dot);
        float d = zn + cn[j] - 2.f * dot;
        if (d < best) { best = d; bj = j; }   // strict <: first-min tie rule
    }
    // butterfly reduce across the 64-lane wave; ties -> smaller index
    #pragma unroll
    for (int off = 1; off < 64; off <<= 1) {
        float ob = __shfl_xor(best, off);
        int   oj = __shfl_xor(bj, off);
        if (ob < best || (ob == best && oj < bj)) { best = ob; bj = oj; }
    }
    if (lane < 32) q[(size_t)row * 32 + lane] = cb[(size_t)bj * 32 + lane];
    if (lane == 0) idxf[row] = (float)bj;
}

// ===================== conv transpose k4 s2 p1 =============================
// == conv over 2x-dilated input with pad 2. Thread computes a 2x2 output
// tile at rows (2i,2i+1) cols (2j,2j+1) from a 3x3 input patch around (i,j).
template <bool TANH>
__global__ __launch_bounds__(256) void convt4(
    const float* __restrict__ x, const float* __restrict__ w,
    const float* __restrict__ bias, float* __restrict__ y,
    int N, int Cin, int Cout, int Hin, int Win)
{
    const int bpp = (Hin * Win) >> 8;
    const int plane = blockIdx.x / bpp;
    const int pb = blockIdx.x - plane * bpp;
    const int co = plane % Cout;              // scalar
    const int n  = plane / Cout;              // scalar
    const int local = pb * 256 + threadIdx.x;
    const int j = local % Win;
    const int i = local / Win;

    const float* __restrict__ xn  = x + (size_t)n * Cin * Hin * Win;
    const float* __restrict__ wp0 = w + (size_t)co * Cin * 16;

    const bool rm0 = (i > 0), rm2 = (i + 1 < Hin);
    const bool cm0 = (j > 0), cm2 = (j + 1 < Win);

    float a00 = 0.f, a01 = 0.f, a10 = 0.f, a11 = 0.f;

    if (rm0 && rm2 && cm0 && cm2) {
        for (int ci = 0; ci < Cin; ++ci) {
            const float* xp = xn + ((size_t)ci * Hin + i) * Win + j;
            float x00 = xp[-Win - 1], x01 = xp[-Win], x02 = xp[-Win + 1];
            float x10 = xp[-1],       x11 = xp[0],    x12 = xp[1];
            float x20 = xp[Win - 1],  x21 = xp[Win],  x22 = xp[Win + 1];
            const float* wp = wp0 + ci * 16;
            float w00 = wp[0],  w01 = wp[1],  w02 = wp[2],  w03 = wp[3];
            float w10 = wp[4],  w11 = wp[5],  w12 = wp[6],  w13 = wp[7];
            float w20 = wp[8],  w21 = wp[9],  w22 = wp[10], w23 = wp[11];
            float w30 = wp[12], w31 = wp[13], w32 = wp[14], w33 = wp[15];
            a00 = fmaf(x00, w00, a00); a00 = fmaf(x01, w02, a00);
            a00 = fmaf(x10, w20, a00); a00 = fmaf(x11, w22, a00);
            a01 = fmaf(x01, w01, a01); a01 = fmaf(x02, w03, a01);
            a01 = fmaf(x11, w21, a01); a01 = fmaf(x12, w23, a01);
            a10 = fmaf(x10, w10, a10); a10 = fmaf(x11, w12, a10);
            a10 = fmaf(x20, w30, a10); a10 = fmaf(x21, w32, a10);
            a11 = fmaf(x11, w11, a11); a11 = fmaf(x12, w13, a11);
            a11 = fmaf(x21, w31, a11); a11 = fmaf(x22, w33, a11);
        }
    } else {
        const int rO0 = rm0 ? -Win : 0;
        const int rO2 = rm2 ?  Win : 0;
        const int cO0 = cm0 ? -1 : 0;
        const int cO2 = cm2 ?  1 : 0;
        for (int ci = 0; ci < Cin; ++ci) {
            const float* xp = xn + ((size_t)ci * Hin + i) * Win + j;
            float x00 = (rm0 && cm0) ? xp[rO0 + cO0] : 0.f;
            float x01 =  rm0         ? xp[rO0]       : 0.f;
            float x02 = (rm0 && cm2) ? xp[rO0 + cO2] : 0.f;
            float x10 =  cm0         ? xp[cO0]       : 0.f;
            float x11 =                xp[0];
            float x12 =  cm2         ? xp[cO2]       : 0.f;
            float x20 = (rm2 && cm0) ? xp[rO2 + cO0] : 0.f;
            float x21 =  rm2         ? xp[rO2]       : 0.f;
            float x22 = (rm2 && cm2) ? xp[rO2 + cO2] : 0.f;
            const float* wp = wp0 + ci * 16;
            float w00 = wp[0],  w01 = wp[1],  w02 = wp[2],  w03 = wp[3];
            float w10 = wp[4],  w11 = wp[5],  w12 = wp[6],  w13 = wp[7];
            float w20 = wp[8],  w21 = wp[9],  w22 = wp[10], w23 = wp[11];
            float w30 = wp[12], w31 = wp[13], w32 = wp[14], w33 = wp[15];
            a00 = fmaf(x00, w00, a00); a00 = fmaf(x01, w02, a00);
            a00 = fmaf(x10, w20, a00); a00 = fmaf(x11, w22, a00);
            a01 = fmaf(x01, w01, a01); a01 = fmaf(x02, w03, a01);
            a01 = fmaf(x11, w21, a01); a01 = fmaf(x12, w23, a01);
            a10 = fmaf(x10, w10, a10); a10 = fmaf(x11, w12, a10);
            a10 = fmaf(x20, w30, a10); a10 = fmaf(x21, w32, a10);
            a11 = fmaf(x11, w11, a11); a11 = fmaf(x12, w13, a11);
            a11 = fmaf(x21, w31, a11); a11 = fmaf(x22, w33, a11);
        }
    }

    const float b = bias[co];
    a00 += b; a01 += b; a10 += b; a11 += b;
    if (TANH) {
        a00 = tanhf(a00); a01 = tanhf(a01);
        a10 = tanhf(a10); a11 = tanhf(a11);
    }
    const int Hout = Hin << 1, Wout = Win << 1;
    float* yp = y + ((size_t)plane * Hout + (i << 1)) * Wout + (j << 1);
    float2 r0; r0.x = a00; r0.y = a01;
    float2 r1; r1.x = a10; r1.y = a11;
    *(float2*)yp = r0;
    *(float2*)(yp + Wout) = r1;
}

// ================================ launch ===================================
extern "C" void kernel_launch(void* const* d_in, const int* in_sizes, int n_in,
                              void* d_out, int out_size, void* d_ws, size_t ws_size,
                              hipStream_t stream)
{
    const float* x       = (const float*)d_in[0];
    const float* enc0_w  = (const float*)d_in[1];
    const float* enc0_b  = (const float*)d_in[2];
    const float* enc0_g  = (const float*)d_in[3];
    const float* enc0_bt = (const float*)d_in[4];
    const float* enc1_w  = (const float*)d_in[5];
    const float* enc1_b  = (const float*)d_in[6];
    const float* enc1_g  = (const float*)d_in[7];
    const float* enc1_bt = (const float*)d_in[8];
    const float* enc2_w  = (const float*)d_in[9];
    const float* enc2_b  = (const float*)d_in[10];
    const float* enc2_g  = (const float*)d_in[11];
    const float* enc2_bt = (const float*)d_in[12];
    const float* enc3_w  = (const float*)d_in[13];
    const float* enc3_b  = (const float*)d_in[14];
    const float* codebook= (const float*)d_in[15];
    const float* dec0_w  = (const float*)d_in[16];
    const float* dec0_b  = (const float*)d_in[17];
    const float* dec1_w  = (const float*)d_in[18];
    const float* dec1_b  = (const float*)d_in[19];
    const float* dec1_g  = (const float*)d_in[20];
    const float* dec1_bt = (const float*)d_in[21];
    const float* dec2_w  = (const float*)d_in[22];
    const float* dec2_b  = (const float*)d_in[23];
    const float* dec2_g  = (const float*)d_in[24];
    const float* dec2_bt = (const float*)d_in[25];
    const float* dec3_w  = (const float*)d_in[26];
    const float* dec3_b  = (const float*)d_in[27];

    float* ws = (float*)d_ws;
    float* A  = ws;                      // 33,554,432 floats (134 MB)
    float* B  = ws + 33554432;           // 16,777,216 floats (67 MB)
    float* C  = ws + 50331648;           //  8,388,608 floats (33.6 MB)
    float* Z  = ws + 58720256;           //    524,288 floats (2 MB)
    float* CN = ws + 59244544;           //      1,024 floats

    float* out   = (float*)d_out;
    float* recon = out;                  // 3,145,728 floats
    float* qbuf  = out + 3145728;        //   524,288 floats
    float* idxf  = out + 3670016;        //    16,384 floats

    const dim3 blk(256);

    // ---------------- encoder ----------------
    // enc0: 16x3x256x256 -> 16x128x128x128
    conv4s2<<<dim3(16 * 128 * ((128 * 32) >> 8)), blk, 0, stream>>>(
        x, enc0_w, enc0_b, A, 16, 3, 128, 256, 256, 128, 128);
    gn_silu<<<dim3(16 * 32), blk, 0, stream>>>(A, enc0_g, enc0_bt, 128, 14, 4);

    // enc1: -> 16x256x64x64
    conv4s2<<<dim3(16 * 256 * ((64 * 16) >> 8)), blk, 0, stream>>>(
        A, enc1_w, enc1_b, B, 16, 128, 256, 128, 128, 64, 64);
    gn_silu<<<dim3(16 * 32), blk, 0, stream>>>(B, enc1_g, enc1_bt, 256, 12, 8);

    // enc2: -> 16x512x32x32
    conv4s2<<<dim3(16 * 512 * ((32 * 8) >> 8)), blk, 0, stream>>>(
        B, enc2_w, enc2_b, C, 16, 256, 512, 64, 64, 32, 32);
    gn_silu<<<dim3(16 * 32), blk, 0, stream>>>(C, enc2_g, enc2_bt, 512, 10, 16);

    // enc3 1x1: -> z 16x32x32x32
    conv1x1<<<dim3(16 * 32 * 4), blk, 0, stream>>>(
        C, enc3_w, enc3_b, Z, 16, 512, 32, 1024);

    // ---------------- VQ ----------------
    cb_norm<<<dim3(4), blk, 0, stream>>>(codebook, CN);
    vq_kernel<<<dim3(16384 / 4), blk, 0, stream>>>(Z, codebook, CN, qbuf, idxf);

    // ---------------- decoder ----------------
    // dec0 1x1: q -> 16x512x32x32 (into A, free now)
    conv1x1<<<dim3(16 * 512 * 4), blk, 0, stream>>>(
        qbuf, dec0_w, dec0_b, A, 16, 32, 512, 1024);

    // dec1 convT: -> 16x256x64x64 (into B)
    convt4<false><<<dim3(16 * 256 * ((32 * 32) >> 8)), blk, 0, stream>>>(
        A, dec1_w, dec1_b, B, 16, 512, 256, 32, 32);
    gn_silu<<<dim3(16 * 32), blk, 0, stream>>>(B, dec1_g, dec1_bt, 256, 12, 8);

    // dec2 convT: -> 16x128x128x128 (into A)
    convt4<false><<<dim3(16 * 128 * ((64 * 64) >> 8)), blk, 0, stream>>>(
        B, dec2_w, dec2_b, A, 16, 256, 128, 64, 64);
    gn_silu<<<dim3(16 * 32), blk, 0, stream>>>(A, dec2_g, dec2_bt, 128, 14, 4);

    // dec3 convT + tanh: -> recon 16x3x256x256
    convt4<true><<<dim3(16 * 3 * ((128 * 128) >> 8)), blk, 0, stream>>>(
        A, dec3_w, dec3_b, recon, 16, 128, 3, 128, 128);
}

// Round 2
// 12681.171 us; speedup vs baseline: 3.3514x; 3.3514x over previous
//
#include <hip/hip_runtime.h>
#include <hip/hip_bf16.h>
#include <math.h>

// ---------------------------------------------------------------------------
// VQGAN forward, fp32, round 2: output-channel-tiled convs (CO_T=8).
// Each thread holds its input patch in registers and accumulates CO_T output
// channels; weights are wave-uniform -> scalar loads. FMA order per output is
// identical to round 1 (ci -> kh -> kw), so numerics match the passing run.
// d_out = [recon 16*3*256*256 | q 16*32*32*32 | idx-as-float 16384]
// ---------------------------------------------------------------------------

#define EPS 1e-5f

// ===================== conv k4 s2 p1, CO_T channels/thread =================
// Thread computes 4 consecutive ow for one (n, oh) and CO_T output channels.
template <int CO_T>
__global__ __launch_bounds__(256) void conv4s2_t(
    const float* __restrict__ x, const float* __restrict__ w,
    const float* __restrict__ bias, float* __restrict__ y,
    int N, int Cin, int Cout, int Hin, int Win, int Hout, int Wout)
{
    const int Wt  = Wout >> 2;
    const int bpp = (Hout * Wt) >> 8;        // blocks per (n, co-group)
    const int plane = blockIdx.x / bpp;      // scalar
    const int pb = blockIdx.x - plane * bpp; // scalar
    const int Cg = Cout / CO_T;
    const int cog = plane % Cg;              // scalar
    const int n   = plane / Cg;              // scalar
    const int co0 = cog * CO_T;
    const int local = pb * 256 + threadIdx.x;
    const int wt = local % Wt;
    const int oh = local / Wt;
    const int iw0 = (wt << 3) - 1;
    const int ih0 = (oh << 1) - 1;

    const float* __restrict__ wbase = w + (size_t)co0 * Cin * 16;
    const float* __restrict__ xn    = x + (size_t)n * Cin * Hin * Win;

    float acc[CO_T][4];
    #pragma unroll
    for (int u = 0; u < CO_T; ++u)
        acc[u][0] = acc[u][1] = acc[u][2] = acc[u][3] = 0.f;

    const bool interior = (ih0 >= 0) && (ih0 + 3 < Hin) && (iw0 >= 0) && (iw0 + 9 < Win);

    if (interior) {
        for (int ci = 0; ci < Cin; ++ci) {
            const float* xp = xn + (size_t)ci * Hin * Win + (size_t)ih0 * Win + iw0;
            #pragma unroll
            for (int kh = 0; kh < 4; ++kh) {
                float xv[10];
                #pragma unroll
                for (int jj = 0; jj < 10; ++jj) xv[jj] = xp[kh * Win + jj];
                #pragma unroll
                for (int u = 0; u < CO_T; ++u) {
                    const float* wp = wbase + ((size_t)u * Cin + ci) * 16 + kh * 4;
                    #pragma unroll
                    for (int kw = 0; kw < 4; ++kw) {
                        float wv = wp[kw];
                        acc[u][0] = fmaf(xv[kw + 0], wv, acc[u][0]);
                        acc[u][1] = fmaf(xv[kw + 2], wv, acc[u][1]);
                        acc[u][2] = fmaf(xv[kw + 4], wv, acc[u][2]);
                        acc[u][3] = fmaf(xv[kw + 6], wv, acc[u][3]);
                    }
                }
            }
        }
    } else {
        bool rv[4]; int ro[4];
        #pragma unroll
        for (int k = 0; k < 4; ++k) {
            int r = ih0 + k;
            rv[k] = (r >= 0) && (r < Hin);
            ro[k] = rv[k] ? r : 0;
        }
        bool cv[10]; int cc[10];
        #pragma unroll
        for (int jj = 0; jj < 10; ++jj) {
            int c = iw0 + jj;
            cv[jj] = (c >= 0) && (c < Win);
            cc[jj] = cv[jj] ? c : 0;
        }
        for (int ci = 0; ci < Cin; ++ci) {
            const float* xp = xn + (size_t)ci * Hin * Win;
            #pragma unroll
            for (int kh = 0; kh < 4; ++kh) {
                float xv[10];
                #pragma unroll
                for (int jj = 0; jj < 10; ++jj) {
                    float v = xp[(size_t)ro[kh] * Win + cc[jj]];
                    xv[jj] = (rv[kh] && cv[jj]) ? v : 0.f;
                }
                #pragma unroll
                for (int u = 0; u < CO_T; ++u) {
                    const float* wp = wbase + ((size_t)u * Cin + ci) * 16 + kh * 4;
                    #pragma unroll
                    for (int kw = 0; kw < 4; ++kw) {
                        float wv = wp[kw];
                        acc[u][0] = fmaf(xv[kw + 0], wv, acc[u][0]);
                        acc[u][1] = fmaf(xv[kw + 2], wv, acc[u][1]);
                        acc[u][2] = fmaf(xv[kw + 4], wv, acc[u][2]);
                        acc[u][3] = fmaf(xv[kw + 6], wv, acc[u][3]);
                    }
                }
            }
        }
    }

    #pragma unroll
    for (int u = 0; u < CO_T; ++u) {
        float b = bias[co0 + u];
        float4 o;
        o.x = acc[u][0] + b; o.y = acc[u][1] + b;
        o.z = acc[u][2] + b; o.w = acc[u][3] + b;
        float* yp = y + (((size_t)(n * Cout + co0 + u)) * Hout + oh) * Wout + (wt << 2);
        *(float4*)yp = o;
    }
}

// ======================= GroupNorm(32) + SiLU, in place ====================
__global__ __launch_bounds__(256) void gn_silu(
    float* __restrict__ y, const float* __restrict__ gamma,
    const float* __restrict__ beta, int C, int HWshift, int grpC)
{
    const int b = blockIdx.x >> 5;
    const int g = blockIdx.x & 31;
    const size_t base = ((size_t)b * C + (size_t)g * grpC) << HWshift;
    const int count4 = (grpC << HWshift) >> 2;
    float4* y4 = (float4*)(y + base);

    float s = 0.f, ss = 0.f;
    for (int i = threadIdx.x; i < count4; i += 256) {
        float4 v = y4[i];
        s += v.x + v.y + v.z + v.w;
        ss = fmaf(v.x, v.x, ss); ss = fmaf(v.y, v.y, ss);
        ss = fmaf(v.z, v.z, ss); ss = fmaf(v.w, v.w, ss);
    }
    __shared__ float sh0[256];
    __shared__ float sh1[256];
    sh0[threadIdx.x] = s; sh1[threadIdx.x] = ss;
    __syncthreads();
    for (int off = 128; off > 0; off >>= 1) {
        if (threadIdx.x < off) {
            sh0[threadIdx.x] += sh0[threadIdx.x + off];
            sh1[threadIdx.x] += sh1[threadIdx.x + off];
        }
        __syncthreads();
    }
    const float inv = 1.f / (float)(count4 * 4);
    const float mean = sh0[0] * inv;
    const float var  = sh1[0] * inv - mean * mean;
    const float rstd = rsqrtf(var + EPS);

    const int HW4shift = HWshift - 2;            // float4s per channel
    for (int i = threadIdx.x; i < count4; i += 256) {
        int c = g * grpC + (i >> HW4shift);
        float ga = gamma[c], be = beta[c];
        float4 v = y4[i];
        float t0 = (v.x - mean) * rstd * ga + be;
        float t1 = (v.y - mean) * rstd * ga + be;
        float t2 = (v.z - mean) * rstd * ga + be;
        float t3 = (v.w - mean) * rstd * ga + be;
        v.x = t0 / (1.f + __expf(-t0));
        v.y = t1 / (1.f + __expf(-t1));
        v.z = t2 / (1.f + __expf(-t2));
        v.w = t3 / (1.f + __expf(-t3));
        y4[i] = v;
    }
}

// ====================== 1x1 conv, CO_T channels/thread =====================
template <int CO_T>
__global__ __launch_bounds__(256) void conv1x1_t(
    const float* __restrict__ x, const float* __restrict__ w,
    const float* __restrict__ bias, float* __restrict__ y,
    int N, int Cin, int Cout, int HW)
{
    const int bpp = HW >> 8;
    const int plane = blockIdx.x / bpp;
    const int pb = blockIdx.x - plane * bpp;
    const int Cg = Cout / CO_T;
    const int cog = plane % Cg;
    const int n   = plane / Cg;
    const int co0 = cog * CO_T;
    const int s = pb * 256 + threadIdx.x;
    const float* xp = x + (size_t)n * Cin * HW + s;

    float acc[CO_T];
    #pragma unroll
    for (int u = 0; u < CO_T; ++u) acc[u] = bias[co0 + u];

    for (int ci = 0; ci < Cin; ++ci) {
        float v = xp[(size_t)ci * HW];
        #pragma unroll
        for (int u = 0; u < CO_T; ++u)
            acc[u] = fmaf(v, w[(size_t)(co0 + u) * Cin + ci], acc[u]);
    }
    #pragma unroll
    for (int u = 0; u < CO_T; ++u)
        y[(size_t)(n * Cout + co0 + u) * HW + s] = acc[u];
}

// ============================== VQ lookup ==================================
__global__ __launch_bounds__(256) void cb_norm(
    const float* __restrict__ cb, float* __restrict__ cn)
{
    int j = blockIdx.x * 256 + threadIdx.x;   // 1024 total
    const float* c = cb + (size_t)j * 32;
    float s = 0.f;
    #pragma unroll
    for (int k = 0; k < 32; ++k) s = fmaf(c[k], c[k], s);
    cn[j] = s;
}

__global__ __launch_bounds__(256) void vq_kernel(
    const float* __restrict__ z, const float* __restrict__ cb,
    const float* __restrict__ cn, float* __restrict__ q,
    float* __restrict__ idxf)
{
    const int row = blockIdx.x * 4 + (threadIdx.x >> 6);
    const int lane = threadIdx.x & 63;
    const float* zr = z + (size_t)row * 32;
    float zreg[32];
    #pragma unroll
    for (int k = 0; k < 32; ++k) zreg[k] = zr[k];
    float zn = 0.f;
    #pragma unroll
    for (int k = 0; k < 32; ++k) zn = fmaf(zreg[k], zreg[k], zn);

    float best = 3.4e38f;
    int bj = 0;
    for (int ii = 0; ii < 16; ++ii) {
        int j = lane * 16 + ii;               // lane-ascending code order
        const float* c = cb + (size_t)j * 32;
        float dot = 0.f;
        #pragma unroll
        for (int k = 0; k < 32; ++k) dot = fmaf(zreg[k], c[k], dot);
        float d = zn + cn[j] - 2.f * dot;
        if (d < best) { best = d; bj = j; }
    }
    #pragma unroll
    for (int off = 1; off < 64; off <<= 1) {
        float ob = __shfl_xor(best, off);
        int   oj = __shfl_xor(bj, off);
        if (ob < best || (ob == best && oj < bj)) { best = ob; bj = oj; }
    }
    if (lane < 32) q[(size_t)row * 32 + lane] = cb[(size_t)bj * 32 + lane];
    if (lane == 0) idxf[row] = (float)bj;
}

// ============ conv transpose k4 s2 p1, CO_T channels/thread ================
template <int CO_T, bool TANH>
__global__ __launch_bounds__(256) void convt4_t(
    const float* __restrict__ x, const float* __restrict__ w,
    const float* __restrict__ bias, float* __restrict__ y,
    int N, int Cin, int Cout, int Hin, int Win)
{
    const int bpp = (Hin * Win) >> 8;
    const int plane = blockIdx.x / bpp;
    const int pb = blockIdx.x - plane * bpp;
    const int Cg = Cout / CO_T;
    const int cog = plane % Cg;
    const int n   = plane / Cg;
    const int co0 = cog * CO_T;
    const int local = pb * 256 + threadIdx.x;
    const int j = local % Win;
    const int i = local / Win;

    const float* __restrict__ xn    = x + (size_t)n * Cin * Hin * Win;
    const float* __restrict__ wbase = w + (size_t)co0 * Cin * 16;

    const bool rm0 = (i > 0), rm2 = (i + 1 < Hin);
    const bool cm0 = (j > 0), cm2 = (j + 1 < Win);

    float acc[CO_T][4];
    #pragma unroll
    for (int u = 0; u < CO_T; ++u)
        acc[u][0] = acc[u][1] = acc[u][2] = acc[u][3] = 0.f;

    if (rm0 && rm2 && cm0 && cm2) {
        for (int ci = 0; ci < Cin; ++ci) {
            const float* xp = xn + ((size_t)ci * Hin + i) * Win + j;
            float x00 = xp[-Win - 1], x01 = xp[-Win], x02 = xp[-Win + 1];
            float x10 = xp[-1],       x11 = xp[0],    x12 = xp[1];
            float x20 = xp[Win - 1],  x21 = xp[Win],  x22 = xp[Win + 1];
            #pragma unroll
            for (int u = 0; u < CO_T; ++u) {
                const float* wp = wbase + ((size_t)u * Cin + ci) * 16;
                float w00 = wp[0],  w01 = wp[1],  w02 = wp[2],  w03 = wp[3];
                float w10 = wp[4],  w11 = wp[5],  w12 = wp[6],  w13 = wp[7];
                float w20 = wp[8],  w21 = wp[9],  w22 = wp[10], w23 = wp[11];
                float w30 = wp[12], w31 = wp[13], w32 = wp[14], w33 = wp[15];
                acc[u][0] = fmaf(x00, w00, acc[u][0]); acc[u][0] = fmaf(x01, w02, acc[u][0]);
                acc[u][0] = fmaf(x10, w20, acc[u][0]); acc[u][0] = fmaf(x11, w22, acc[u][0]);
                acc[u][1] = fmaf(x01, w01, acc[u][1]); acc[u][1] = fmaf(x02, w03, acc[u][1]);
                acc[u][1] = fmaf(x11, w21, acc[u][1]); acc[u][1] = fmaf(x12, w23, acc[u][1]);
                acc[u][2] = fmaf(x10, w10, acc[u][2]); acc[u][2] = fmaf(x11, w12, acc[u][2]);
                acc[u][2] = fmaf(x20, w30, acc[u][2]); acc[u][2] = fmaf(x21, w32, acc[u][2]);
                acc[u][3] = fmaf(x11, w11, acc[u][3]); acc[u][3] = fmaf(x12, w13, acc[u][3]);
                acc[u][3] = fmaf(x21, w31, acc[u][3]); acc[u][3] = fmaf(x22, w33, acc[u][3]);
            }
        }
    } else {
        const int rO0 = rm0 ? -Win : 0;
        const int rO2 = rm2 ?  Win : 0;
        const int cO0 = cm0 ? -1 : 0;
        const int cO2 = cm2 ?  1 : 0;
        for (int ci = 0; ci < Cin; ++ci) {
            const float* xp = xn + ((size_t)ci * Hin + i) * Win + j;
            float x00 = (rm0 && cm0) ? xp[rO0 + cO0] : 0.f;
            float x01 =  rm0         ? xp[rO0]       : 0.f;
            float x02 = (rm0 && cm2) ? xp[rO0 + cO2] : 0.f;
            float x10 =  cm0         ? xp[cO0]       : 0.f;
            float x11 =                xp[0];
            float x12 =  cm2         ? xp[cO2]       : 0.f;
            float x20 = (rm2 && cm0) ? xp[rO2 + cO0] : 0.f;
            float x21 =  rm2         ? xp[rO2]       : 0.f;
            float x22 = (rm2 && cm2) ? xp[rO2 + cO2] : 0.f;
            #pragma unroll
            for (int u = 0; u < CO_T; ++u) {
                const float* wp = wbase + ((size_t)u * Cin + ci) * 16;
                float w00 = wp[0],  w01 = wp[1],  w02 = wp[2],  w03 = wp[3];
                float w10 = wp[4],  w11 = wp[5],  w12 = wp[6],  w13 = wp[7];
                float w20 = wp[8],  w21 = wp[9],  w22 = wp[10], w23 = wp[11];
                float w30 = wp[12], w31 = wp[13], w32 = wp[14], w33 = wp[15];
                acc[u][0] = fmaf(x00, w00, acc[u][0]); acc[u][0] = fmaf(x01, w02, acc[u][0]);
                acc[u][0] = fmaf(x10, w20, acc[u][0]); acc[u][0] = fmaf(x11, w22, acc[u][0]);
                acc[u][1] = fmaf(x01, w01, acc[u][1]); acc[u][1] = fmaf(x02, w03, acc[u][1]);
                acc[u][1] = fmaf(x11, w21, acc[u][1]); acc[u][1] = fmaf(x12, w23, acc[u][1]);
                acc[u][2] = fmaf(x10, w10, acc[u][2]); acc[u][2] = fmaf(x11, w12, acc[u][2]);
                acc[u][2] = fmaf(x20, w30, acc[u][2]); acc[u][2] = fmaf(x21, w32, acc[u][2]);
                acc[u][3] = fmaf(x11, w11, acc[u][3]); acc[u][3] = fmaf(x12, w13, acc[u][3]);
                acc[u][3] = fmaf(x21, w31, acc[u][3]); acc[u][3] = fmaf(x22, w33, acc[u][3]);
            }
        }
    }

    const int Hout = Hin << 1, Wout = Win << 1;
    #pragma unroll
    for (int u = 0; u < CO_T; ++u) {
        float b = bias[co0 + u];
        float a00 = acc[u][0] + b, a01 = acc[u][1] + b;
        float a10 = acc[u][2] + b, a11 = acc[u][3] + b;
        if (TANH) {
            a00 = tanhf(a00); a01 = tanhf(a01);
            a10 = tanhf(a10); a11 = tanhf(a11);
        }
        float* yp = y + (((size_t)(n * Cout + co0 + u)) * Hout + (i << 1)) * Wout + (j << 1);
        float2 r0; r0.x = a00; r0.y = a01;
        float2 r1; r1.x = a10; r1.y = a11;
        *(float2*)yp = r0;
        *(float2*)(yp + Wout) = r1;
    }
}

// ================================ launch ===================================
extern "C" void kernel_launch(void* const* d_in, const int* in_sizes, int n_in,
                              void* d_out, int out_size, void* d_ws, size_t ws_size,
                              hipStream_t stream)
{
    const float* x       = (const float*)d_in[0];
    const float* enc0_w  = (const float*)d_in[1];
    const float* enc0_b  = (const float*)d_in[2];
    const float* enc0_g  = (const float*)d_in[3];
    const float* enc0_bt = (const float*)d_in[4];
    const float* enc1_w  = (const float*)d_in[5];
    const float* enc1_b  = (const float*)d_in[6];
    const float* enc1_g  = (const float*)d_in[7];
    const float* enc1_bt = (const float*)d_in[8];
    const float* enc2_w  = (const float*)d_in[9];
    const float* enc2_b  = (const float*)d_in[10];
    const float* enc2_g  = (const float*)d_in[11];
    const float* enc2_bt = (const float*)d_in[12];
    const float* enc3_w  = (const float*)d_in[13];
    const float* enc3_b  = (const float*)d_in[14];
    const float* codebook= (const float*)d_in[15];
    const float* dec0_w  = (const float*)d_in[16];
    const float* dec0_b  = (const float*)d_in[17];
    const float* dec1_w  = (const float*)d_in[18];
    const float* dec1_b  = (const float*)d_in[19];
    const float* dec1_g  = (const float*)d_in[20];
    const float* dec1_bt = (const float*)d_in[21];
    const float* dec2_w  = (const float*)d_in[22];
    const float* dec2_b  = (const float*)d_in[23];
    const float* dec2_g  = (const float*)d_in[24];
    const float* dec2_bt = (const float*)d_in[25];
    const float* dec3_w  = (const float*)d_in[26];
    const float* dec3_b  = (const float*)d_in[27];

    float* ws = (float*)d_ws;
    float* A  = ws;                      // 33,554,432 floats (134 MB)
    float* B  = ws + 33554432;           // 16,777,216 floats (67 MB)
    float* C  = ws + 50331648;           //  8,388,608 floats (33.6 MB)
    float* Z  = ws + 58720256;           //    524,288 floats (2 MB)
    float* CN = ws + 59244544;           //      1,024 floats

    float* out   = (float*)d_out;
    float* recon = out;                  // 3,145,728 floats
    float* qbuf  = out + 3145728;        //   524,288 floats
    float* idxf  = out + 3670016;        //    16,384 floats

    const dim3 blk(256);

    // ---------------- encoder ----------------
    // enc0: 16x3x256x256 -> 16x128x128x128  (Cg=16, bpp=16)
    conv4s2_t<8><<<dim3(16 * 16 * 16), blk, 0, stream>>>(
        x, enc0_w, enc0_b, A, 16, 3, 128, 256, 256, 128, 128);
    gn_silu<<<dim3(16 * 32), blk, 0, stream>>>(A, enc0_g, enc0_bt, 128, 14, 4);

    // enc1: -> 16x256x64x64  (Cg=32, bpp=4)
    conv4s2_t<8><<<dim3(16 * 32 * 4), blk, 0, stream>>>(
        A, enc1_w, enc1_b, B, 16, 128, 256, 128, 128, 64, 64);
    gn_silu<<<dim3(16 * 32), blk, 0, stream>>>(B, enc1_g, enc1_bt, 256, 12, 8);

    // enc2: -> 16x512x32x32  (Cg=64, bpp=1)
    conv4s2_t<8><<<dim3(16 * 64 * 1), blk, 0, stream>>>(
        B, enc2_w, enc2_b, C, 16, 256, 512, 64, 64, 32, 32);
    gn_silu<<<dim3(16 * 32), blk, 0, stream>>>(C, enc2_g, enc2_bt, 512, 10, 16);

    // enc3 1x1: -> z 16x32x32x32  (Cg=4, bpp=4)
    conv1x1_t<8><<<dim3(16 * 4 * 4), blk, 0, stream>>>(
        C, enc3_w, enc3_b, Z, 16, 512, 32, 1024);

    // ---------------- VQ ----------------
    cb_norm<<<dim3(4), blk, 0, stream>>>(codebook, CN);
    vq_kernel<<<dim3(16384 / 4), blk, 0, stream>>>(Z, codebook, CN, qbuf, idxf);

    // ---------------- decoder ----------------
    // dec0 1x1: q -> 16x512x32x32 (into A)  (Cg=64, bpp=4)
    conv1x1_t<8><<<dim3(16 * 64 * 4), blk, 0, stream>>>(
        qbuf, dec0_w, dec0_b, A, 16, 32, 512, 1024);

    // dec1 convT: -> 16x256x64x64 (into B)  (Cg=32, bpp=4)
    convt4_t<8, false><<<dim3(16 * 32 * 4), blk, 0, stream>>>(
        A, dec1_w, dec1_b, B, 16, 512, 256, 32, 32);
    gn_silu<<<dim3(16 * 32), blk, 0, stream>>>(B, dec1_g, dec1_bt, 256, 12, 8);

    // dec2 convT: -> 16x128x128x128 (into A)  (Cg=16, bpp=16)
    convt4_t<8, false><<<dim3(16 * 16 * 16), blk, 0, stream>>>(
        B, dec2_w, dec2_b, A, 16, 256, 128, 64, 64);
    gn_silu<<<dim3(16 * 32), blk, 0, stream>>>(A, dec2_g, dec2_bt, 128, 14, 4);

    // dec3 convT + tanh: -> recon 16x3x256x256  (Cg=1, bpp=64)
    convt4_t<3, true><<<dim3(16 * 1 * 64), blk, 0, stream>>>(
        A, dec3_w, dec3_b, recon, 16, 128, 3, 128, 128);
}

// Round 3
// 4997.187 us; speedup vs baseline: 8.5046x; 2.5377x over previous
//
#include <hip/hip_runtime.h>
#include <hip/hip_bf16.h>
#include <math.h>

// ---------------------------------------------------------------------------
// VQGAN forward, fp32, round 3: fully templated convs + 3D grid.
// blockIdx.z = batch, blockIdx.y = output-channel group -> co0/n are SGPRs,
// weight addresses wave-uniform -> s_load on the scalar pipe. No runtime
// integer division anywhere. Single-path boundary masking (cndmask), no
// divergent double execution. FMA order per output = ci -> kh -> kw,
// identical to rounds 1-2 (bit-identical numerics).
// d_out = [recon 16*3*256*256 | q 16*32*32*32 | idx-as-float 16384]
// ---------------------------------------------------------------------------

#define EPS 1e-5f

// ===================== conv k4 s2 p1, CO_T channels/thread =================
// Thread computes 4 consecutive ow for one (n, oh) and CO_T output channels.
template <int Cin, int Cout, int Hin, int Win, int CO_T>
__global__ __launch_bounds__(256) void conv4s2_k(
    const float* __restrict__ x, const float* __restrict__ w,
    const float* __restrict__ bias, float* __restrict__ y)
{
    constexpr int Hout = Hin / 2, Wout = Win / 2, Wt = Wout / 4;
    const int n   = blockIdx.z;              // SGPR
    const int co0 = blockIdx.y * CO_T;       // SGPR
    const int local = blockIdx.x * 256 + threadIdx.x;
    const int wt = local & (Wt - 1);
    const int oh = local / Wt;               // Wt is pow2 -> shift
    const int iw0 = (wt << 3) - 1;
    const int ih0 = (oh << 1) - 1;

    const float* __restrict__ xn = x + (size_t)n * Cin * Hin * Win;
    const float* __restrict__ wb = w + (size_t)co0 * Cin * 16;

    const bool cL = (wt > 0);                // col j=0 valid
    const bool cR = (wt < Wt - 1);           // col j=9 valid

    float acc[CO_T][4];
    #pragma unroll
    for (int u = 0; u < CO_T; ++u)
        acc[u][0] = acc[u][1] = acc[u][2] = acc[u][3] = 0.f;

    bool rv[4]; int ro[4];
    #pragma unroll
    for (int k = 0; k < 4; ++k) {
        int r = ih0 + k;
        rv[k] = (r >= 0) && (r < Hin);
        ro[k] = rv[k] ? r : 0;
    }

    for (int ci = 0; ci < Cin; ++ci) {
        const float* xp = xn + (size_t)ci * Hin * Win;
        float xv[4][10];
        #pragma unroll
        for (int k = 0; k < 4; ++k) {
            const float* rp = xp + (size_t)ro[k] * Win;
            // middle 8 columns always in-bounds: two aligned float4 loads
            float4 m0 = *(const float4*)(rp + (wt << 3));
            float4 m1 = *(const float4*)(rp + (wt << 3) + 4);
            float e0 = cL ? rp[iw0] : 0.f;
            float e9 = cR ? rp[iw0 + 9] : 0.f;
            float v1 = m0.x, v2 = m0.y, v3 = m0.z, v4 = m0.w;
            float v5 = m1.x, v6 = m1.y, v7 = m1.z, v8 = m1.w;
            bool rk = rv[k];
            xv[k][0] = rk ? e0 : 0.f;
            xv[k][1] = rk ? v1 : 0.f;
            xv[k][2] = rk ? v2 : 0.f;
            xv[k][3] = rk ? v3 : 0.f;
            xv[k][4] = rk ? v4 : 0.f;
            xv[k][5] = rk ? v5 : 0.f;
            xv[k][6] = rk ? v6 : 0.f;
            xv[k][7] = rk ? v7 : 0.f;
            xv[k][8] = rk ? v8 : 0.f;
            xv[k][9] = rk ? e9 : 0.f;
        }
        #pragma unroll
        for (int u = 0; u < CO_T; ++u) {
            const float* wp = wb + ((size_t)u * Cin + ci) * 16;  // uniform
            #pragma unroll
            for (int kh = 0; kh < 4; ++kh) {
                #pragma unroll
                for (int kw = 0; kw < 4; ++kw) {
                    float wv = wp[kh * 4 + kw];
                    acc[u][0] = fmaf(xv[kh][kw + 0], wv, acc[u][0]);
                    acc[u][1] = fmaf(xv[kh][kw + 2], wv, acc[u][1]);
                    acc[u][2] = fmaf(xv[kh][kw + 4], wv, acc[u][2]);
                    acc[u][3] = fmaf(xv[kh][kw + 6], wv, acc[u][3]);
                }
            }
        }
    }

    #pragma unroll
    for (int u = 0; u < CO_T; ++u) {
        float b = bias[co0 + u];
        float4 o;
        o.x = acc[u][0] + b; o.y = acc[u][1] + b;
        o.z = acc[u][2] + b; o.w = acc[u][3] + b;
        float* yp = y + (((size_t)(n * Cout + co0 + u)) * Hout + oh) * Wout + (wt << 2);
        *(float4*)yp = o;
    }
}

// ======================= GroupNorm(32) + SiLU, in place ====================
__global__ __launch_bounds__(256) void gn_silu(
    float* __restrict__ y, const float* __restrict__ gamma,
    const float* __restrict__ beta, int C, int HWshift, int grpC)
{
    const int b = blockIdx.x >> 5;
    const int g = blockIdx.x & 31;
    const size_t base = ((size_t)b * C + (size_t)g * grpC) << HWshift;
    const int count4 = (grpC << HWshift) >> 2;
    float4* y4 = (float4*)(y + base);

    float s = 0.f, ss = 0.f;
    for (int i = threadIdx.x; i < count4; i += 256) {
        float4 v = y4[i];
        s += v.x + v.y + v.z + v.w;
        ss = fmaf(v.x, v.x, ss); ss = fmaf(v.y, v.y, ss);
        ss = fmaf(v.z, v.z, ss); ss = fmaf(v.w, v.w, ss);
    }
    __shared__ float sh0[256];
    __shared__ float sh1[256];
    sh0[threadIdx.x] = s; sh1[threadIdx.x] = ss;
    __syncthreads();
    for (int off = 128; off > 0; off >>= 1) {
        if (threadIdx.x < off) {
            sh0[threadIdx.x] += sh0[threadIdx.x + off];
            sh1[threadIdx.x] += sh1[threadIdx.x + off];
        }
        __syncthreads();
    }
    const float inv = 1.f / (float)(count4 * 4);
    const float mean = sh0[0] * inv;
    const float var  = sh1[0] * inv - mean * mean;
    const float rstd = rsqrtf(var + EPS);

    const int HW4shift = HWshift - 2;
    for (int i = threadIdx.x; i < count4; i += 256) {
        int c = g * grpC + (i >> HW4shift);
        float ga = gamma[c], be = beta[c];
        float4 v = y4[i];
        float t0 = (v.x - mean) * rstd * ga + be;
        float t1 = (v.y - mean) * rstd * ga + be;
        float t2 = (v.z - mean) * rstd * ga + be;
        float t3 = (v.w - mean) * rstd * ga + be;
        v.x = t0 / (1.f + __expf(-t0));
        v.y = t1 / (1.f + __expf(-t1));
        v.z = t2 / (1.f + __expf(-t2));
        v.w = t3 / (1.f + __expf(-t3));
        y4[i] = v;
    }
}

// ====================== 1x1 conv, CO_T channels/thread =====================
template <int Cin, int Cout, int HW, int CO_T>
__global__ __launch_bounds__(256) void conv1x1_k(
    const float* __restrict__ x, const float* __restrict__ w,
    const float* __restrict__ bias, float* __restrict__ y)
{
    const int n   = blockIdx.z;
    const int co0 = blockIdx.y * CO_T;
    const int s = blockIdx.x * 256 + threadIdx.x;
    const float* xp = x + (size_t)n * Cin * HW + s;

    float acc[CO_T];
    #pragma unroll
    for (int u = 0; u < CO_T; ++u) acc[u] = bias[co0 + u];

    for (int ci = 0; ci < Cin; ++ci) {
        float v = xp[(size_t)ci * HW];
        #pragma unroll
        for (int u = 0; u < CO_T; ++u)
            acc[u] = fmaf(v, w[(size_t)(co0 + u) * Cin + ci], acc[u]);
    }
    #pragma unroll
    for (int u = 0; u < CO_T; ++u)
        y[(size_t)(n * Cout + co0 + u) * HW + s] = acc[u];
}

// ============================== VQ lookup ==================================
__global__ __launch_bounds__(256) void cb_norm(
    const float* __restrict__ cb, float* __restrict__ cn)
{
    int j = blockIdx.x * 256 + threadIdx.x;   // 1024 total
    const float* c = cb + (size_t)j * 32;
    float s = 0.f;
    #pragma unroll
    for (int k = 0; k < 32; ++k) s = fmaf(c[k], c[k], s);
    cn[j] = s;
}

__global__ __launch_bounds__(256) void vq_kernel(
    const float* __restrict__ z, const float* __restrict__ cb,
    const float* __restrict__ cn, float* __restrict__ q,
    float* __restrict__ idxf)
{
    const int row = blockIdx.x * 4 + (threadIdx.x >> 6);
    const int lane = threadIdx.x & 63;
    const float* zr = z + (size_t)row * 32;
    float zreg[32];
    #pragma unroll
    for (int k = 0; k < 32; ++k) zreg[k] = zr[k];
    float zn = 0.f;
    #pragma unroll
    for (int k = 0; k < 32; ++k) zn = fmaf(zreg[k], zreg[k], zn);

    float best = 3.4e38f;
    int bj = 0;
    for (int ii = 0; ii < 16; ++ii) {
        int j = lane * 16 + ii;               // lane-ascending code order
        const float* c = cb + (size_t)j * 32;
        float dot = 0.f;
        #pragma unroll
        for (int k = 0; k < 32; ++k) dot = fmaf(zreg[k], c[k], dot);
        float d = zn + cn[j] - 2.f * dot;
        if (d < best) { best = d; bj = j; }
    }
    #pragma unroll
    for (int off = 1; off < 64; off <<= 1) {
        float ob = __shfl_xor(best, off);
        int   oj = __shfl_xor(bj, off);
        if (ob < best || (ob == best && oj < bj)) { best = ob; bj = oj; }
    }
    if (lane < 32) q[(size_t)row * 32 + lane] = cb[(size_t)bj * 32 + lane];
    if (lane == 0) idxf[row] = (float)bj;
}

// ============ conv transpose k4 s2 p1, CO_T channels/thread ================
template <int Cin, int Cout, int Hin, int Win, int CO_T, bool TANH>
__global__ __launch_bounds__(256) void convt4_k(
    const float* __restrict__ x, const float* __restrict__ w,
    const float* __restrict__ bias, float* __restrict__ y)
{
    const int n   = blockIdx.z;              // SGPR
    const int co0 = blockIdx.y * CO_T;       // SGPR
    const int local = blockIdx.x * 256 + threadIdx.x;
    const int j = local & (Win - 1);
    const int i = local / Win;               // Win pow2 -> shift

    const float* __restrict__ xn = x + (size_t)n * Cin * Hin * Win;
    const float* __restrict__ wb = w + (size_t)co0 * Cin * 16;

    const bool rm0 = (i > 0), rm2 = (i + 1 < Hin);
    const bool cm0 = (j > 0), cm2 = (j + 1 < Win);
    const int rO0 = rm0 ? -Win : 0;
    const int rO2 = rm2 ?  Win : 0;
    const int cO0 = cm0 ? -1 : 0;
    const int cO2 = cm2 ?  1 : 0;

    float acc[CO_T][4];
    #pragma unroll
    for (int u = 0; u < CO_T; ++u)
        acc[u][0] = acc[u][1] = acc[u][2] = acc[u][3] = 0.f;

    for (int ci = 0; ci < Cin; ++ci) {
        const float* xp = xn + ((size_t)ci * Hin + i) * Win + j;
        float x00 = (rm0 && cm0) ? xp[rO0 + cO0] : 0.f;
        float x01 =  rm0         ? xp[rO0]       : 0.f;
        float x02 = (rm0 && cm2) ? xp[rO0 + cO2] : 0.f;
        float x10 =  cm0         ? xp[cO0]       : 0.f;
        float x11 =                xp[0];
        float x12 =  cm2         ? xp[cO2]       : 0.f;
        float x20 = (rm2 && cm0) ? xp[rO2 + cO0] : 0.f;
        float x21 =  rm2         ? xp[rO2]       : 0.f;
        float x22 = (rm2 && cm2) ? xp[rO2 + cO2] : 0.f;
        #pragma unroll
        for (int u = 0; u < CO_T; ++u) {
            const float* wp = wb + ((size_t)u * Cin + ci) * 16;  // uniform
            float w00 = wp[0],  w01 = wp[1],  w02 = wp[2],  w03 = wp[3];
            float w10 = wp[4],  w11 = wp[5],  w12 = wp[6],  w13 = wp[7];
            float w20 = wp[8],  w21 = wp[9],  w22 = wp[10], w23 = wp[11];
            float w30 = wp[12], w31 = wp[13], w32 = wp[14], w33 = wp[15];
            acc[u][0] = fmaf(x00, w00, acc[u][0]); acc[u][0] = fmaf(x01, w02, acc[u][0]);
            acc[u][0] = fmaf(x10, w20, acc[u][0]); acc[u][0] = fmaf(x11, w22, acc[u][0]);
            acc[u][1] = fmaf(x01, w01, acc[u][1]); acc[u][1] = fmaf(x02, w03, acc[u][1]);
            acc[u][1] = fmaf(x11, w21, acc[u][1]); acc[u][1] = fmaf(x12, w23, acc[u][1]);
            acc[u][2] = fmaf(x10, w10, acc[u][2]); acc[u][2] = fmaf(x11, w12, acc[u][2]);
            acc[u][2] = fmaf(x20, w30, acc[u][2]); acc[u][2] = fmaf(x21, w32, acc[u][2]);
            acc[u][3] = fmaf(x11, w11, acc[u][3]); acc[u][3] = fmaf(x12, w13, acc[u][3]);
            acc[u][3] = fmaf(x21, w31, acc[u][3]); acc[u][3] = fmaf(x22, w33, acc[u][3]);
        }
    }

    constexpr int Hout = Hin * 2, Wout = Win * 2;
    #pragma unroll
    for (int u = 0; u < CO_T; ++u) {
        float b = bias[co0 + u];
        float a00 = acc[u][0] + b, a01 = acc[u][1] + b;
        float a10 = acc[u][2] + b, a11 = acc[u][3] + b;
        if (TANH) {
            a00 = tanhf(a00); a01 = tanhf(a01);
            a10 = tanhf(a10); a11 = tanhf(a11);
        }
        float* yp = y + (((size_t)(n * Cout + co0 + u)) * Hout + (i << 1)) * Wout + (j << 1);
        float2 r0; r0.x = a00; r0.y = a01;
        float2 r1; r1.x = a10; r1.y = a11;
        *(float2*)yp = r0;
        *(float2*)(yp + Wout) = r1;
    }
}

// ================================ launch ===================================
extern "C" void kernel_launch(void* const* d_in, const int* in_sizes, int n_in,
                              void* d_out, int out_size, void* d_ws, size_t ws_size,
                              hipStream_t stream)
{
    const float* x       = (const float*)d_in[0];
    const float* enc0_w  = (const float*)d_in[1];
    const float* enc0_b  = (const float*)d_in[2];
    const float* enc0_g  = (const float*)d_in[3];
    const float* enc0_bt = (const float*)d_in[4];
    const float* enc1_w  = (const float*)d_in[5];
    const float* enc1_b  = (const float*)d_in[6];
    const float* enc1_g  = (const float*)d_in[7];
    const float* enc1_bt = (const float*)d_in[8];
    const float* enc2_w  = (const float*)d_in[9];
    const float* enc2_b  = (const float*)d_in[10];
    const float* enc2_g  = (const float*)d_in[11];
    const float* enc2_bt = (const float*)d_in[12];
    const float* enc3_w  = (const float*)d_in[13];
    const float* enc3_b  = (const float*)d_in[14];
    const float* codebook= (const float*)d_in[15];
    const float* dec0_w  = (const float*)d_in[16];
    const float* dec0_b  = (const float*)d_in[17];
    const float* dec1_w  = (const float*)d_in[18];
    const float* dec1_b  = (const float*)d_in[19];
    const float* dec1_g  = (const float*)d_in[20];
    const float* dec1_bt = (const float*)d_in[21];
    const float* dec2_w  = (const float*)d_in[22];
    const float* dec2_b  = (const float*)d_in[23];
    const float* dec2_g  = (const float*)d_in[24];
    const float* dec2_bt = (const float*)d_in[25];
    const float* dec3_w  = (const float*)d_in[26];
    const float* dec3_b  = (const float*)d_in[27];

    float* ws = (float*)d_ws;
    float* A  = ws;                      // 33,554,432 floats (134 MB)
    float* B  = ws + 33554432;           // 16,777,216 floats (67 MB)
    float* C  = ws + 50331648;           //  8,388,608 floats (33.6 MB)
    float* Z  = ws + 58720256;           //    524,288 floats (2 MB)
    float* CN = ws + 59244544;           //      1,024 floats

    float* out   = (float*)d_out;
    float* recon = out;                  // 3,145,728 floats
    float* qbuf  = out + 3145728;        //   524,288 floats
    float* idxf  = out + 3670016;        //    16,384 floats

    const dim3 blk(256);

    // ---------------- encoder ----------------
    // enc0: 16x3x256x256 -> 16x128x128x128   spatial=16, Cg=16, N=16
    conv4s2_k<3, 128, 256, 256, 8><<<dim3(16, 16, 16), blk, 0, stream>>>(
        x, enc0_w, enc0_b, A);
    gn_silu<<<dim3(16 * 32), blk, 0, stream>>>(A, enc0_g, enc0_bt, 128, 14, 4);

    // enc1: -> 16x256x64x64   spatial=4, Cg=32, N=16
    conv4s2_k<128, 256, 128, 128, 8><<<dim3(4, 32, 16), blk, 0, stream>>>(
        A, enc1_w, enc1_b, B);
    gn_silu<<<dim3(16 * 32), blk, 0, stream>>>(B, enc1_g, enc1_bt, 256, 12, 8);

    // enc2: -> 16x512x32x32   spatial=1, Cg=64, N=16
    conv4s2_k<256, 512, 64, 64, 8><<<dim3(1, 64, 16), blk, 0, stream>>>(
        B, enc2_w, enc2_b, C);
    gn_silu<<<dim3(16 * 32), blk, 0, stream>>>(C, enc2_g, enc2_bt, 512, 10, 16);

    // enc3 1x1: -> z 16x32x32x32   spatial=4, Cg=4, N=16
    conv1x1_k<512, 32, 1024, 8><<<dim3(4, 4, 16), blk, 0, stream>>>(
        C, enc3_w, enc3_b, Z);

    // ---------------- VQ ----------------
    cb_norm<<<dim3(4), blk, 0, stream>>>(codebook, CN);
    vq_kernel<<<dim3(16384 / 4), blk, 0, stream>>>(Z, codebook, CN, qbuf, idxf);

    // ---------------- decoder ----------------
    // dec0 1x1: q -> 16x512x32x32 (into A)   spatial=4, Cg=64, N=16
    conv1x1_k<32, 512, 1024, 8><<<dim3(4, 64, 16), blk, 0, stream>>>(
        qbuf, dec0_w, dec0_b, A);

    // dec1 convT: -> 16x256x64x64 (into B)   spatial=4, Cg=32, N=16
    convt4_k<512, 256, 32, 32, 8, false><<<dim3(4, 32, 16), blk, 0, stream>>>(
        A, dec1_w, dec1_b, B);
    gn_silu<<<dim3(16 * 32), blk, 0, stream>>>(B, dec1_g, dec1_bt, 256, 12, 8);

    // dec2 convT: -> 16x128x128x128 (into A)   spatial=16, Cg=16, N=16
    convt4_k<256, 128, 64, 64, 8, false><<<dim3(16, 16, 16), blk, 0, stream>>>(
        B, dec2_w, dec2_b, A);
    gn_silu<<<dim3(16 * 32), blk, 0, stream>>>(A, dec2_g, dec2_bt, 128, 14, 4);

    // dec3 convT + tanh: -> recon 16x3x256x256   spatial=64, Cg=1, N=16
    convt4_k<128, 3, 128, 128, 3, true><<<dim3(64, 1, 16), blk, 0, stream>>>(
        A, dec3_w, dec3_b, recon);
}